// Round 1
// baseline (589.812 us; speedup 1.0000x reference)
//
#include <hip/hip_runtime.h>
#include <hip/hip_bf16.h>

#define T_TOK   16384
#define HID     4096
#define NEXP    64
#define NTOPK   8
#define CAPACITY 2048
#define TE      (T_TOK * NEXP)      // 1048576
#define NBLK2   (T_TOK / 64)        // 256 routing blocks

// ---------------- K0: transpose gate weight [64,4096] -> Wt[4096,64] ----------
__global__ __launch_bounds__(256) void transpose_w_k(const float* __restrict__ wg,
                                                     float* __restrict__ wt) {
    int o = blockIdx.x * 256 + threadIdx.x;   // 0 .. 262143
    int k = o >> 6, e = o & 63;
    wt[o] = wg[(size_t)e * HID + k];
}

// ---------------- K1: gate GEMM  logits_part[split][t][e] --------------------
// grid (T/64, 2), block 256.  lane = token, wave w handles experts [16w,16w+16)
__global__ __launch_bounds__(256) void gemm_k(const float* __restrict__ x,
                                              const float* __restrict__ wt,
                                              float* __restrict__ lp) {
    __shared__ float xs[64][64];              // [k][t], 16 KB
    const int tid  = threadIdx.x;
    const int lane = tid & 63;
    const int ebase = __builtin_amdgcn_readfirstlane(tid >> 6) * 16;
    const int t0    = blockIdx.x * 64;
    const int kbase = blockIdx.y * (HID / 2);
    const int tl = tid >> 2;                  // staging token 0..63
    const int kq = (tid & 3) << 4;            // staging k sub-offset

    float acc[16];
#pragma unroll
    for (int j = 0; j < 16; ++j) acc[j] = 0.f;

    for (int tile = 0; tile < (HID / 2) / 64; ++tile) {
        const int k0 = kbase + tile * 64;
        float4 v[4];
        const float4* gp = (const float4*)(x + (size_t)(t0 + tl) * HID + k0 + kq);
#pragma unroll
        for (int j = 0; j < 4; ++j) v[j] = gp[j];
        __syncthreads();
#pragma unroll
        for (int j = 0; j < 4; ++j) {
            xs[kq + j * 4 + 0][tl] = v[j].x;
            xs[kq + j * 4 + 1][tl] = v[j].y;
            xs[kq + j * 4 + 2][tl] = v[j].z;
            xs[kq + j * 4 + 3][tl] = v[j].w;
        }
        __syncthreads();
        const float* wr = wt + (size_t)k0 * NEXP + ebase;
#pragma unroll 4
        for (int k = 0; k < 64; ++k) {
            const float xk = xs[k][lane];
            const float4* wp = (const float4*)(wr + (size_t)k * NEXP);
            float4 w0 = wp[0], w1 = wp[1], w2 = wp[2], w3 = wp[3];
            acc[0]  = fmaf(w0.x, xk, acc[0]);
            acc[1]  = fmaf(w0.y, xk, acc[1]);
            acc[2]  = fmaf(w0.z, xk, acc[2]);
            acc[3]  = fmaf(w0.w, xk, acc[3]);
            acc[4]  = fmaf(w1.x, xk, acc[4]);
            acc[5]  = fmaf(w1.y, xk, acc[5]);
            acc[6]  = fmaf(w1.z, xk, acc[6]);
            acc[7]  = fmaf(w1.w, xk, acc[7]);
            acc[8]  = fmaf(w2.x, xk, acc[8]);
            acc[9]  = fmaf(w2.y, xk, acc[9]);
            acc[10] = fmaf(w2.z, xk, acc[10]);
            acc[11] = fmaf(w2.w, xk, acc[11]);
            acc[12] = fmaf(w3.x, xk, acc[12]);
            acc[13] = fmaf(w3.y, xk, acc[13]);
            acc[14] = fmaf(w3.z, xk, acc[14]);
            acc[15] = fmaf(w3.w, xk, acc[15]);
        }
    }
    float4* op = (float4*)(lp + (size_t)blockIdx.y * TE + (size_t)(t0 + lane) * NEXP + ebase);
    op[0] = make_float4(acc[0],  acc[1],  acc[2],  acc[3]);
    op[1] = make_float4(acc[4],  acc[5],  acc[6],  acc[7]);
    op[2] = make_float4(acc[8],  acc[9],  acc[10], acc[11]);
    op[3] = make_float4(acc[12], acc[13], acc[14], acc[15]);
}

// ---------------- K2: softmax + group-limited top-k routing -------------------
// grid T/64, block 256 (4 waves x 16 tokens each). lane = expert.
__global__ __launch_bounds__(256) void route_k(const float* __restrict__ lp,
                                               int* __restrict__ ws_idx,
                                               float* __restrict__ ws_prob,
                                               int* __restrict__ ws_rank,
                                               int* __restrict__ ws_hist,
                                               float* __restrict__ ws_gsum) {
    __shared__ unsigned char idx_lds[64][8];
    __shared__ int hist_lds[512];
    __shared__ float gsum_lds[4][64];
    const int tid = threadIdx.x, lane = tid & 63, w = tid >> 6;
    const int blk = blockIdx.x;
    for (int i = tid; i < 512; i += 256) hist_lds[i] = 0;
    __syncthreads();

    float gacc = 0.f;
    for (int i = 0; i < 16; ++i) {
        const int tloc = w * 16 + i;
        const int t = blk * 64 + tloc;
        float lg = lp[(size_t)t * NEXP + lane] + lp[(size_t)TE + (size_t)t * NEXP + lane];
        // softmax over 64 experts
        float m = lg;
#pragma unroll
        for (int off = 32; off; off >>= 1) m = fmaxf(m, __shfl_xor(m, off));
        float p = expf(lg - m);
        float s = p;
#pragma unroll
        for (int off = 32; off; off >>= 1) s += __shfl_xor(s, off);
        float gate = p / s;
        // group scores (max over 8 lanes within group), then top-4 groups
        float gsc = gate;
#pragma unroll
        for (int off = 1; off < 8; off <<= 1) gsc = fmaxf(gsc, __shfl_xor(gsc, off));
        const int g = lane >> 3;
        int grank = 0;
#pragma unroll
        for (int gg = 0; gg < 8; ++gg) {
            float o = __shfl(gsc, gg * 8);
            grank += (o > gsc || (o == gsc && gg < g)) ? 1 : 0;
        }
        float gm = (grank < 4) ? gate : 0.f;
        gacc += gm;  // masked gates feed l_aux mean
        // top-8 over 64 lanes; key ties broken toward LOWER lane (lax.top_k)
        unsigned long long key =
            ((unsigned long long)__float_as_uint(gm) << 32) | (unsigned long long)(63 - lane);
        float dsum = 0.f;
        int my_e = 0; float my_v = 0.f;
#pragma unroll
        for (int r = 0; r < NTOPK; ++r) {
            unsigned long long b = key;
#pragma unroll
            for (int off = 32; off; off >>= 1) {
                unsigned long long o = __shfl_xor(b, off);
                b = (o > b) ? o : b;
            }
            int be = 63 - (int)(b & 63ull);
            float bv = __uint_as_float((unsigned)(b >> 32));
            dsum += bv;
            if (lane == r) { my_e = be; my_v = bv; }
            if (lane == be) key = 0ull;
        }
        float denom = fmaxf(dsum, 1.1920929e-7f);  // clip(sum, float32 eps)
        if (lane < NTOPK) {
            ws_idx[(size_t)t * NTOPK + lane]  = my_e;
            ws_prob[(size_t)t * NTOPK + lane] = my_v / denom;
            idx_lds[tloc][lane] = (unsigned char)my_e;
            atomicAdd(&hist_lds[lane * NEXP + my_e], 1);
        }
    }
    gsum_lds[w][lane] = gacc;
    __syncthreads();
    // within-block ranks (token order, slot-major cumsum semantics)
    for (int pp = tid; pp < 512; pp += 256) {
        const int tloc = pp >> 3, k = pp & 7;
        const int e = idx_lds[tloc][k];
        int cnt = 0;
        for (int tp = 0; tp < tloc; ++tp) cnt += (idx_lds[tp][k] == e) ? 1 : 0;
        ws_rank[(size_t)(blk * 64 + tloc) * NTOPK + k] = cnt;
    }
    for (int i = tid; i < 512; i += 256) ws_hist[(size_t)blk * 512 + i] = hist_lds[i];
    if (tid < 64)
        ws_gsum[(size_t)blk * NEXP + tid] =
            gsum_lds[0][tid] + gsum_lds[1][tid] + gsum_lds[2][tid] + gsum_lds[3][tid];
}

// ---------------- K3a: per-bin exclusive scan over 256 blocks -----------------
__global__ void scan_k(const int* __restrict__ hist, int* __restrict__ offs,
                       int* __restrict__ tot) {
    const int bin = blockIdx.x * blockDim.x + threadIdx.x;  // 0..511
    int run = 0;
    for (int b = 0; b < NBLK2; ++b) {
        int v = hist[(size_t)b * 512 + bin];
        offs[(size_t)b * 512 + bin] = run;
        run += v;
    }
    tot[bin] = run;
}

// ---------------- K3b: slot bases + scalar outputs ----------------------------
__global__ __launch_bounds__(256) void finalize_k(const int* __restrict__ tot,
                                                  const float* __restrict__ gsum,
                                                  int* __restrict__ base,
                                                  float* __restrict__ out) {
    __shared__ int tl[512];
    const int tid = threadIdx.x;
    for (int i = tid; i < 512; i += 256) tl[i] = tot[i];
    __syncthreads();
    for (int i = tid; i < 512; i += 256) {
        const int k = i >> 6, e = i & 63;
        int b = 0;
        for (int kk = 0; kk < k; ++kk) b += tl[kk * NEXP + e];
        base[i] = b;
    }
    if (tid < 64) {
        int cnt = 0;
#pragma unroll
        for (int k = 0; k < NTOPK; ++k) cnt += tl[k * NEXP + tid];
        out[2 + 3 * TE + tid] = (float)cnt;          // exp_counts
        float sg = 0.f;
        for (int b = 0; b < NBLK2; ++b) sg += gsum[(size_t)b * NEXP + tid];
        float lx = (float)cnt * sg;
        int vs = cnt < CAPACITY ? cnt : CAPACITY;
#pragma unroll
        for (int off = 32; off; off >>= 1) {
            lx += __shfl_xor(lx, off);
            vs += __shfl_xor(vs, off);
        }
        if (tid == 0) {
            out[0] = 64.0f * lx / 268435456.0f;      // E^2 * mean = 64*sum/T^2
            out[1] = (float)vs / 131072.0f;          // / (T*TOPK)
        }
    }
}

// ---------------- K4: dense [T,64] combine / priority / valid -----------------
__global__ __launch_bounds__(256) void output_k(const int* __restrict__ ws_idx,
                                                const float* __restrict__ ws_prob,
                                                const int* __restrict__ ws_rank,
                                                const int* __restrict__ offs,
                                                const int* __restrict__ base,
                                                float* __restrict__ out) {
    const int gid = blockIdx.x * 256 + threadIdx.x;   // 0..TE-1
    const int t = gid >> 6, e = gid & 63;
    int i8[NTOPK];
#pragma unroll
    for (int k = 0; k < NTOPK; ++k) i8[k] = ws_idx[(size_t)t * NTOPK + k];
    int found = -1;
#pragma unroll
    for (int k = 0; k < NTOPK; ++k) if (i8[k] == e) found = k;
    float cw = 0.f, pr = 0.f, vm = 0.f;
    if (found >= 0) {
        const int bin = found * NEXP + e;
        int pos = base[bin] + offs[(size_t)(t >> 6) * 512 + bin] +
                  ws_rank[(size_t)t * NTOPK + found];
        if (pos < CAPACITY) {
            cw = ws_prob[(size_t)t * NTOPK + found];
            pr = (float)pos;
            vm = 1.f;
        }
    }
    out[2 + gid]          = cw;   // combine_weights
    out[2 + TE + gid]     = pr;   // token_priority (as float)
    out[2 + 2 * TE + gid] = vm;   // valid_mask (as 0/1 float)
}

// ---------------- launch ------------------------------------------------------
extern "C" void kernel_launch(void* const* d_in, const int* in_sizes, int n_in,
                              void* d_out, int out_size, void* d_ws, size_t ws_size,
                              hipStream_t stream) {
    const float* x  = (const float*)d_in[0];   // [16384, 4096] fp32
    const float* wg = (const float*)d_in[1];   // [64, 4096] fp32
    float* out = (float*)d_out;
    char* ws = (char*)d_ws;

    // workspace layout (16B aligned, ~11.6 MB total)
    float* wt   = (float*)(ws + 0);            // 1 MB
    float* lp   = (float*)(ws + 1048576);      // 8 MB (2 K-split partials)
    int*   idxw = (int*)  (ws + 9437184);      // 512 KB
    float* prob = (float*)(ws + 9961472);      // 512 KB
    int*   rank = (int*)  (ws + 10485760);     // 512 KB
    int*   hist = (int*)  (ws + 11010048);     // 512 KB
    int*   offs = (int*)  (ws + 11534336);     // 512 KB
    float* gsum = (float*)(ws + 12058624);     // 64 KB
    int*   tot  = (int*)  (ws + 12124160);     // 2 KB
    int*   base = (int*)  (ws + 12126208);     // 2 KB

    transpose_w_k<<<(HID * NEXP) / 256, 256, 0, stream>>>(wg, wt);
    dim3 g1(T_TOK / 64, 2);
    gemm_k<<<g1, 256, 0, stream>>>(x, wt, lp);
    route_k<<<NBLK2, 256, 0, stream>>>(lp, idxw, prob, rank, hist, gsum);
    scan_k<<<2, 256, 0, stream>>>(hist, offs, tot);
    finalize_k<<<1, 256, 0, stream>>>(tot, gsum, base, out);
    output_k<<<TE / 256, 256, 0, stream>>>(idxw, prob, rank, offs, base, out);
}

// Round 2
// 496.104 us; speedup vs baseline: 1.1889x; 1.1889x over previous
//
#include <hip/hip_runtime.h>
#include <hip/hip_bf16.h>

#define T_TOK   16384
#define HID     4096
#define NEXP    64
#define NTOPK   8
#define CAPACITY 2048
#define TE      (T_TOK * NEXP)      // 1048576
#define NBLK2   (T_TOK / 64)        // 256 routing blocks

// ---------------- K1: gate GEMM  lp[split][t][e] ------------------------------
// grid (T/64, KS), block 256. Tile: 64 tokens x 64 experts x klen K.
// Thread (tx=tid&15, ty=tid>>4) computes 4 tokens x 4 experts.
__global__ __launch_bounds__(256) void gemm_k(const float* __restrict__ x,
                                              const float* __restrict__ wg,
                                              float* __restrict__ lp, int klen) {
    __shared__ float xs[64][64];   // [k][t] 16 KB
    __shared__ float wsh[64][64];  // [k][e] 16 KB
    const int tid = threadIdx.x;
    const int tx = tid & 15, ty = tid >> 4;          // expert quad / token quad
    const int t0 = blockIdx.x * 64;
    const int kbase = blockIdx.y * klen;
    const int stl = tid >> 2;                        // staging row 0..63
    const int skq = (tid & 3) << 4;                  // staging k sub-offset

    float acc[4][4];
#pragma unroll
    for (int i = 0; i < 4; ++i)
#pragma unroll
        for (int j = 0; j < 4; ++j) acc[i][j] = 0.f;

    const int ntiles = klen >> 6;
    for (int tile = 0; tile < ntiles; ++tile) {
        const int k0 = kbase + (tile << 6);
        // prefetch x tile (token stl, k's [skq,skq+16)) and w tile (expert stl)
        float4 xv[4], wv[4];
        const float4* gx = (const float4*)(x + (size_t)(t0 + stl) * HID + k0 + skq);
        const float4* gw = (const float4*)(wg + (size_t)stl * HID + k0 + skq);
#pragma unroll
        for (int j = 0; j < 4; ++j) { xv[j] = gx[j]; wv[j] = gw[j]; }
        __syncthreads();
#pragma unroll
        for (int j = 0; j < 4; ++j) {
            xs[skq + j * 4 + 0][stl] = xv[j].x;
            xs[skq + j * 4 + 1][stl] = xv[j].y;
            xs[skq + j * 4 + 2][stl] = xv[j].z;
            xs[skq + j * 4 + 3][stl] = xv[j].w;
            wsh[skq + j * 4 + 0][stl] = wv[j].x;
            wsh[skq + j * 4 + 1][stl] = wv[j].y;
            wsh[skq + j * 4 + 2][stl] = wv[j].z;
            wsh[skq + j * 4 + 3][stl] = wv[j].w;
        }
        __syncthreads();
#pragma unroll 16
        for (int k = 0; k < 64; ++k) {
            float4 a = *(const float4*)(&xs[k][ty * 4]);
            float4 b = *(const float4*)(&wsh[k][tx * 4]);
            float ar[4] = {a.x, a.y, a.z, a.w};
            float br[4] = {b.x, b.y, b.z, b.w};
#pragma unroll
            for (int i = 0; i < 4; ++i)
#pragma unroll
                for (int j = 0; j < 4; ++j)
                    acc[i][j] = fmaf(ar[i], br[j], acc[i][j]);
        }
    }
    float* op = lp + (size_t)blockIdx.y * TE + (size_t)(t0 + ty * 4) * NEXP + tx * 4;
#pragma unroll
    for (int i = 0; i < 4; ++i)
        *(float4*)(op + (size_t)i * NEXP) =
            make_float4(acc[i][0], acc[i][1], acc[i][2], acc[i][3]);
}

// ---------------- K2: softmax + group-limited top-k routing -------------------
// grid T/64, block 256 (4 waves x 16 tokens each). lane = expert.
__global__ __launch_bounds__(256) void route_k(const float* __restrict__ lp, int ks,
                                               int* __restrict__ ws_idx,
                                               float* __restrict__ ws_prob,
                                               int* __restrict__ ws_rank,
                                               int* __restrict__ ws_hist,
                                               float* __restrict__ ws_gsum) {
    __shared__ unsigned char idx_lds[64][8];
    __shared__ float gsum_lds[4][64];
    const int tid = threadIdx.x, lane = tid & 63, w = tid >> 6;
    const int blk = blockIdx.x;

    float gacc = 0.f;
    for (int i = 0; i < 16; ++i) {
        const int tloc = w * 16 + i;
        const int t = blk * 64 + tloc;
        float lg = 0.f;
        for (int s = 0; s < ks; ++s)
            lg += lp[(size_t)s * TE + (size_t)t * NEXP + lane];
        // softmax over 64 experts
        float m = lg;
#pragma unroll
        for (int off = 32; off; off >>= 1) m = fmaxf(m, __shfl_xor(m, off));
        float p = expf(lg - m);
        float s = p;
#pragma unroll
        for (int off = 32; off; off >>= 1) s += __shfl_xor(s, off);
        float gate = p / s;
        // group scores (max over 8 lanes within group), then top-4 groups
        float gsc = gate;
#pragma unroll
        for (int off = 1; off < 8; off <<= 1) gsc = fmaxf(gsc, __shfl_xor(gsc, off));
        const int g = lane >> 3;
        int grank = 0;
#pragma unroll
        for (int gg = 0; gg < 8; ++gg) {
            float o = __shfl(gsc, gg * 8);
            grank += (o > gsc || (o == gsc && gg < g)) ? 1 : 0;
        }
        float gm = (grank < 4) ? gate : 0.f;
        gacc += gm;
        // top-8 over 64 lanes; ties toward lower lane (lax.top_k)
        unsigned long long key =
            ((unsigned long long)__float_as_uint(gm) << 32) | (unsigned long long)(63 - lane);
        float dsum = 0.f;
        int my_e = 0; float my_v = 0.f;
#pragma unroll
        for (int r = 0; r < NTOPK; ++r) {
            unsigned long long b = key;
#pragma unroll
            for (int off = 32; off; off >>= 1) {
                unsigned long long o = __shfl_xor(b, off);
                b = (o > b) ? o : b;
            }
            int be = 63 - (int)(b & 63ull);
            float bv = __uint_as_float((unsigned)(b >> 32));
            dsum += bv;
            if (lane == r) { my_e = be; my_v = bv; }
            if (lane == be) key = 0ull;
        }
        float denom = fmaxf(dsum, 1.1920929e-7f);
        if (lane < NTOPK) {
            ws_idx[(size_t)t * NTOPK + lane]  = my_e;
            ws_prob[(size_t)t * NTOPK + lane] = my_v / denom;
            idx_lds[tloc][lane] = (unsigned char)my_e;
        }
    }
    gsum_lds[w][lane] = gacc;
    __syncthreads();
    // rank + hist via ballot: wave w handles slots w and w+4; lane = token
    const unsigned long long ltmask = (1ull << lane) - 1ull;
    for (int kk = w; kk < NTOPK; kk += 4) {
        const int ev = idx_lds[lane][kk];
        int rank = 0, hc = 0;
        for (int e0 = 0; e0 < NEXP; ++e0) {
            unsigned long long msk = __ballot(ev == e0);
            if (ev == e0) rank = __popcll(msk & ltmask);
            if (lane == e0) hc = __popcll(msk);
        }
        ws_rank[(size_t)(blk * 64 + lane) * NTOPK + kk] = rank;
        ws_hist[(size_t)(kk * NEXP + lane) * NBLK2 + blk] = hc;  // [bin][block]
    }
    if (tid < 64)
        ws_gsum[(size_t)blk * NEXP + tid] =
            gsum_lds[0][tid] + gsum_lds[1][tid] + gsum_lds[2][tid] + gsum_lds[3][tid];
}

// ---------------- K3a: per-bin exclusive scan, 1 wave per bin -----------------
__global__ __launch_bounds__(512) void scan_k(const int* __restrict__ hist,
                                              int* __restrict__ offs,
                                              int* __restrict__ tot) {
    const int bin = blockIdx.x * 8 + (threadIdx.x >> 6);
    const int lane = threadIdx.x & 63;
    int4 v = ((const int4*)(hist + (size_t)bin * NBLK2))[lane];
    int s = v.x + v.y + v.z + v.w;
    int incl = s;
#pragma unroll
    for (int off = 1; off < 64; off <<= 1) {
        int n = __shfl_up(incl, off);
        if (lane >= off) incl += n;
    }
    int excl = incl - s;
    int4 o;
    o.x = excl; o.y = excl + v.x; o.z = o.y + v.y; o.w = o.z + v.z;
    ((int4*)(offs + (size_t)bin * NBLK2))[lane] = o;
    if (lane == 63) tot[bin] = incl;
}

// ---------------- K3b: slot bases + scalar outputs ----------------------------
__global__ __launch_bounds__(256) void finalize_k(const int* __restrict__ tot,
                                                  const float* __restrict__ gsum,
                                                  int* __restrict__ base,
                                                  float* __restrict__ out) {
    __shared__ int tl[512];
    __shared__ float gl[256];
    const int tid = threadIdx.x;
    for (int i = tid; i < 512; i += 256) tl[i] = tot[i];
    // parallel gsum partial: e = tid&63, quarter q = tid>>6 sums 64 blocks
    {
        const int e = tid & 63, q = tid >> 6;
        float p = 0.f;
        for (int b = q * 64; b < q * 64 + 64; ++b) p += gsum[(size_t)b * NEXP + e];
        gl[tid] = p;
    }
    __syncthreads();
    for (int i = tid; i < 512; i += 256) {
        const int k = i >> 6, e = i & 63;
        int b = 0;
        for (int kk = 0; kk < k; ++kk) b += tl[kk * NEXP + e];
        base[i] = b;
    }
    if (tid < 64) {
        int cnt = 0;
#pragma unroll
        for (int k = 0; k < NTOPK; ++k) cnt += tl[k * NEXP + tid];
        out[2 + 3 * TE + tid] = (float)cnt;          // exp_counts
        float sg = gl[tid] + gl[64 + tid] + gl[128 + tid] + gl[192 + tid];
        float lx = (float)cnt * sg;
        int vs = cnt < CAPACITY ? cnt : CAPACITY;
#pragma unroll
        for (int off = 32; off; off >>= 1) {
            lx += __shfl_xor(lx, off);
            vs += __shfl_xor(vs, off);
        }
        if (tid == 0) {
            out[0] = 64.0f * lx / 268435456.0f;      // E^2 * sum / T^2
            out[1] = (float)vs / 131072.0f;          // / (T*TOPK)
        }
    }
}

// ---------------- K4: dense [T,64] combine / priority / valid -----------------
// thread handles 4 consecutive experts; float4 writes to 3 sections.
__global__ __launch_bounds__(256) void output_k(const int* __restrict__ ws_idx,
                                                const float* __restrict__ ws_prob,
                                                const int* __restrict__ ws_rank,
                                                const int* __restrict__ offs,
                                                const int* __restrict__ base,
                                                float* __restrict__ out) {
    const int gid = blockIdx.x * 256 + threadIdx.x;   // 0..TE/4-1
    const int t = gid >> 4, e0 = (gid & 15) << 2;
    const int4* ip = (const int4*)(ws_idx + (size_t)t * NTOPK);
    int4 ia = ip[0], ib = ip[1];
    int i8[NTOPK] = {ia.x, ia.y, ia.z, ia.w, ib.x, ib.y, ib.z, ib.w};
    float cw[4] = {0.f, 0.f, 0.f, 0.f}, pr[4] = {0.f, 0.f, 0.f, 0.f},
          vm[4] = {0.f, 0.f, 0.f, 0.f};
#pragma unroll
    for (int j = 0; j < 4; ++j) {
        const int e = e0 + j;
        int found = -1;
#pragma unroll
        for (int k = 0; k < NTOPK; ++k) if (i8[k] == e) found = k;
        if (found >= 0) {
            const int bin = found * NEXP + e;
            int pos = base[bin] + offs[(size_t)bin * NBLK2 + (t >> 6)] +
                      ws_rank[(size_t)t * NTOPK + found];
            if (pos < CAPACITY) {
                cw[j] = ws_prob[(size_t)t * NTOPK + found];
                pr[j] = (float)pos;
                vm[j] = 1.f;
            }
        }
    }
    ((float4*)(out + 2))[gid]          = make_float4(cw[0], cw[1], cw[2], cw[3]);
    ((float4*)(out + 2 + TE))[gid]     = make_float4(pr[0], pr[1], pr[2], pr[3]);
    ((float4*)(out + 2 + 2 * TE))[gid] = make_float4(vm[0], vm[1], vm[2], vm[3]);
}

// ---------------- launch ------------------------------------------------------
extern "C" void kernel_launch(void* const* d_in, const int* in_sizes, int n_in,
                              void* d_out, int out_size, void* d_ws, size_t ws_size,
                              hipStream_t stream) {
    const float* x  = (const float*)d_in[0];   // [16384, 4096] fp32
    const float* wg = (const float*)d_in[1];   // [64, 4096] fp32
    float* out = (float*)d_out;
    char* ws = (char*)d_ws;

    // K-split: 4 if workspace allows (16 MB partials), else 2 (8 MB)
    const int KS = (ws_size >= 20u * 1024u * 1024u) ? 4 : 2;
    const size_t lp_bytes = (size_t)KS * TE * 4;

    float* lp   = (float*)(ws);
    char*  rest = ws + lp_bytes;
    int*   idxw = (int*)  (rest);               // 512 KB
    float* prob = (float*)(rest + 524288);      // 512 KB
    int*   rank = (int*)  (rest + 1048576);     // 512 KB
    int*   hist = (int*)  (rest + 1572864);     // 512 KB  [bin][block]
    int*   offs = (int*)  (rest + 2097152);     // 512 KB  [bin][block]
    float* gsum = (float*)(rest + 2621440);     // 64 KB
    int*   tot  = (int*)  (rest + 2686976);     // 2 KB
    int*   base = (int*)  (rest + 2691072);     // 2 KB

    dim3 g1(T_TOK / 64, KS);
    gemm_k<<<g1, 256, 0, stream>>>(x, wg, lp, HID / KS);
    route_k<<<NBLK2, 256, 0, stream>>>(lp, KS, idxw, prob, rank, hist, gsum);
    scan_k<<<64, 512, 0, stream>>>(hist, offs, tot);
    finalize_k<<<1, 256, 0, stream>>>(tot, gsum, base, out);
    output_k<<<TE / 4 / 256, 256, 0, stream>>>(idxw, prob, rank, offs, base, out);
}

// Round 3
// 449.334 us; speedup vs baseline: 1.3126x; 1.1041x over previous
//
#include <hip/hip_runtime.h>
#include <hip/hip_bf16.h>

#define T_TOK   16384
#define HID     4096
#define NEXP    64
#define NTOPK   8
#define CAPACITY 2048
#define TE      (T_TOK * NEXP)      // 1048576
#define NBLK2   (T_TOK / 64)        // 256 routing blocks
#define BT      128                 // tokens per gemm block-tile
#define BK      32                  // K-tile

// ---------------- K1: gate GEMM  lp[split][t][e] ------------------------------
// grid (T/128, KS), block 256. Tile: 128 tokens x 64 experts x BK.
// Thread (tx=tid&15 -> 4 experts, ty=tid>>4 -> 8 tokens).
__global__ __launch_bounds__(256, 4) void gemm_k(const float* __restrict__ x,
                                                 const float* __restrict__ wg,
                                                 float* __restrict__ lp, int klen) {
    __shared__ float xs[BK][BT];    // [k][t] 16 KB
    __shared__ float wsh[BK][NEXP]; // [k][e]  8 KB
    const int tid = threadIdx.x;
    const int tx = tid & 15, ty = tid >> 4;
    const int t0 = blockIdx.x * BT;
    const int kbase = blockIdx.y * klen;
    // staging maps
    const int stx = tid >> 1;           // x token row 0..127
    const int skx = (tid & 1) << 4;     // 16 floats along k
    const int stw = tid >> 2;           // w expert row 0..63
    const int skw = (tid & 3) << 3;     // 8 floats along k

    float acc[8][4];
#pragma unroll
    for (int i = 0; i < 8; ++i)
#pragma unroll
        for (int j = 0; j < 4; ++j) acc[i][j] = 0.f;

    const int ntiles = klen / BK;
    for (int tile = 0; tile < ntiles; ++tile) {
        const int k0 = kbase + tile * BK;
        float4 xv[4], wv[2];
        const float4* gx = (const float4*)(x + (size_t)(t0 + stx) * HID + k0 + skx);
        const float4* gw = (const float4*)(wg + (size_t)stw * HID + k0 + skw);
#pragma unroll
        for (int j = 0; j < 4; ++j) xv[j] = gx[j];
#pragma unroll
        for (int j = 0; j < 2; ++j) wv[j] = gw[j];
        __syncthreads();
#pragma unroll
        for (int j = 0; j < 4; ++j) {
            xs[skx + j * 4 + 0][stx] = xv[j].x;
            xs[skx + j * 4 + 1][stx] = xv[j].y;
            xs[skx + j * 4 + 2][stx] = xv[j].z;
            xs[skx + j * 4 + 3][stx] = xv[j].w;
        }
#pragma unroll
        for (int j = 0; j < 2; ++j) {
            wsh[skw + j * 4 + 0][stw] = wv[j].x;
            wsh[skw + j * 4 + 1][stw] = wv[j].y;
            wsh[skw + j * 4 + 2][stw] = wv[j].z;
            wsh[skw + j * 4 + 3][stw] = wv[j].w;
        }
        __syncthreads();
#pragma unroll
        for (int k = 0; k < BK; ++k) {
            float4 a0 = *(const float4*)(&xs[k][ty * 8]);
            float4 a1 = *(const float4*)(&xs[k][ty * 8 + 4]);
            float4 b  = *(const float4*)(&wsh[k][tx * 4]);
            float ar[8] = {a0.x, a0.y, a0.z, a0.w, a1.x, a1.y, a1.z, a1.w};
            float br[4] = {b.x, b.y, b.z, b.w};
#pragma unroll
            for (int i = 0; i < 8; ++i)
#pragma unroll
                for (int j = 0; j < 4; ++j)
                    acc[i][j] = fmaf(ar[i], br[j], acc[i][j]);
        }
    }
    float* op = lp + (size_t)blockIdx.y * TE + (size_t)(t0 + ty * 8) * NEXP + tx * 4;
#pragma unroll
    for (int i = 0; i < 8; ++i)
        *(float4*)(op + (size_t)i * NEXP) =
            make_float4(acc[i][0], acc[i][1], acc[i][2], acc[i][3]);
}

// ---------------- K2: softmax + group-limited top-k routing -------------------
// grid T/64, block 1024 (16 waves x 4 tokens each). lane = expert.
__global__ __launch_bounds__(1024) void route_k(const float* __restrict__ lp, int ks,
                                                int* __restrict__ ws_idx,
                                                float* __restrict__ ws_prob,
                                                int* __restrict__ ws_rank,
                                                int* __restrict__ ws_hist,
                                                float* __restrict__ ws_gsum) {
    __shared__ unsigned char idx_lds[64][8];
    __shared__ float gsum_lds[16][64];
    const int tid = threadIdx.x, lane = tid & 63, w = tid >> 6;
    const int blk = blockIdx.x;

    float gacc = 0.f;
    for (int i = 0; i < 4; ++i) {
        const int tloc = w * 4 + i;
        const int t = blk * 64 + tloc;
        float lg = 0.f;
        for (int s = 0; s < ks; ++s)
            lg += lp[(size_t)s * TE + (size_t)t * NEXP + lane];
        // softmax over 64 experts
        float m = lg;
#pragma unroll
        for (int off = 32; off; off >>= 1) m = fmaxf(m, __shfl_xor(m, off));
        float p = expf(lg - m);
        float s = p;
#pragma unroll
        for (int off = 32; off; off >>= 1) s += __shfl_xor(s, off);
        float gate = p / s;
        // group scores (max over 8 lanes within group), then top-4 groups
        float gsc = gate;
#pragma unroll
        for (int off = 1; off < 8; off <<= 1) gsc = fmaxf(gsc, __shfl_xor(gsc, off));
        const int g = lane >> 3;
        int grank = 0;
#pragma unroll
        for (int gg = 0; gg < 8; ++gg) {
            float o = __shfl(gsc, gg * 8);
            grank += (o > gsc || (o == gsc && gg < g)) ? 1 : 0;
        }
        float gm = (grank < 4) ? gate : 0.f;
        gacc += gm;
        // top-8 over 64 lanes; ties toward lower lane (lax.top_k)
        unsigned long long key =
            ((unsigned long long)__float_as_uint(gm) << 32) | (unsigned long long)(63 - lane);
        float dsum = 0.f;
        int my_e = 0; float my_v = 0.f;
#pragma unroll
        for (int r = 0; r < NTOPK; ++r) {
            unsigned long long b = key;
#pragma unroll
            for (int off = 32; off; off >>= 1) {
                unsigned long long o = __shfl_xor(b, off);
                b = (o > b) ? o : b;
            }
            int be = 63 - (int)(b & 63ull);
            float bv = __uint_as_float((unsigned)(b >> 32));
            dsum += bv;
            if (lane == r) { my_e = be; my_v = bv; }
            if (lane == be) key = 0ull;
        }
        float denom = fmaxf(dsum, 1.1920929e-7f);
        if (lane < NTOPK) {
            ws_idx[(size_t)t * NTOPK + lane]  = my_e;
            ws_prob[(size_t)t * NTOPK + lane] = my_v / denom;
            idx_lds[tloc][lane] = (unsigned char)my_e;
        }
    }
    gsum_lds[w][lane] = gacc;
    __syncthreads();
    // rank + hist via ballot: wave w<8 handles slot w; lane = token
    if (w < NTOPK) {
        const unsigned long long ltmask = (1ull << lane) - 1ull;
        const int ev = idx_lds[lane][w];
        int rank = 0, hc = 0;
        for (int e0 = 0; e0 < NEXP; ++e0) {
            unsigned long long msk = __ballot(ev == e0);
            if (ev == e0) rank = __popcll(msk & ltmask);
            if (lane == e0) hc = __popcll(msk);
        }
        ws_rank[(size_t)(blk * 64 + lane) * NTOPK + w] = rank;
        ws_hist[(size_t)(w * NEXP + lane) * NBLK2 + blk] = hc;  // [bin][block]
    }
    if (tid < 64) {
        float sg = 0.f;
#pragma unroll
        for (int ww = 0; ww < 16; ++ww) sg += gsum_lds[ww][tid];
        ws_gsum[(size_t)blk * NEXP + tid] = sg;
    }
}

// ---------------- K3a: per-bin exclusive scan, 1 wave per bin -----------------
__global__ __launch_bounds__(512) void scan_k(const int* __restrict__ hist,
                                              int* __restrict__ offs,
                                              int* __restrict__ tot) {
    const int bin = blockIdx.x * 8 + (threadIdx.x >> 6);
    const int lane = threadIdx.x & 63;
    int4 v = ((const int4*)(hist + (size_t)bin * NBLK2))[lane];
    int s = v.x + v.y + v.z + v.w;
    int incl = s;
#pragma unroll
    for (int off = 1; off < 64; off <<= 1) {
        int n = __shfl_up(incl, off);
        if (lane >= off) incl += n;
    }
    int excl = incl - s;
    int4 o;
    o.x = excl; o.y = excl + v.x; o.z = o.y + v.y; o.w = o.z + v.z;
    ((int4*)(offs + (size_t)bin * NBLK2))[lane] = o;
    if (lane == 63) tot[bin] = incl;
}

// ---------------- K3b: slot bases + scalar outputs ----------------------------
__global__ __launch_bounds__(256) void finalize_k(const int* __restrict__ tot,
                                                  const float* __restrict__ gsum,
                                                  int* __restrict__ base,
                                                  float* __restrict__ out) {
    __shared__ int tl[512];
    __shared__ float gl[256];
    const int tid = threadIdx.x;
    for (int i = tid; i < 512; i += 256) tl[i] = tot[i];
    {
        const int e = tid & 63, q = tid >> 6;
        float p = 0.f;
        for (int b = q * 64; b < q * 64 + 64; ++b) p += gsum[(size_t)b * NEXP + e];
        gl[tid] = p;
    }
    __syncthreads();
    for (int i = tid; i < 512; i += 256) {
        const int k = i >> 6, e = i & 63;
        int b = 0;
        for (int kk = 0; kk < k; ++kk) b += tl[kk * NEXP + e];
        base[i] = b;
    }
    if (tid < 64) {
        int cnt = 0;
#pragma unroll
        for (int k = 0; k < NTOPK; ++k) cnt += tl[k * NEXP + tid];
        out[2 + 3 * TE + tid] = (float)cnt;          // exp_counts
        float sg = gl[tid] + gl[64 + tid] + gl[128 + tid] + gl[192 + tid];
        float lx = (float)cnt * sg;
        int vs = cnt < CAPACITY ? cnt : CAPACITY;
#pragma unroll
        for (int off = 32; off; off >>= 1) {
            lx += __shfl_xor(lx, off);
            vs += __shfl_xor(vs, off);
        }
        if (tid == 0) {
            out[0] = 64.0f * lx / 268435456.0f;      // E^2 * sum / T^2
            out[1] = (float)vs / 131072.0f;          // / (T*TOPK)
        }
    }
}

// ---------------- K4: dense [T,64] combine / priority / valid -----------------
__global__ __launch_bounds__(256) void output_k(const int* __restrict__ ws_idx,
                                                const float* __restrict__ ws_prob,
                                                const int* __restrict__ ws_rank,
                                                const int* __restrict__ offs,
                                                const int* __restrict__ base,
                                                float* __restrict__ out) {
    const int gid = blockIdx.x * 256 + threadIdx.x;   // 0..TE/4-1
    const int t = gid >> 4, e0 = (gid & 15) << 2;
    const int4* ip = (const int4*)(ws_idx + (size_t)t * NTOPK);
    int4 ia = ip[0], ib = ip[1];
    int i8[NTOPK] = {ia.x, ia.y, ia.z, ia.w, ib.x, ib.y, ib.z, ib.w};
    float cw[4] = {0.f, 0.f, 0.f, 0.f}, pr[4] = {0.f, 0.f, 0.f, 0.f},
          vm[4] = {0.f, 0.f, 0.f, 0.f};
#pragma unroll
    for (int j = 0; j < 4; ++j) {
        const int e = e0 + j;
        int found = -1;
#pragma unroll
        for (int k = 0; k < NTOPK; ++k) if (i8[k] == e) found = k;
        if (found >= 0) {
            const int bin = found * NEXP + e;
            int pos = base[bin] + offs[(size_t)bin * NBLK2 + (t >> 6)] +
                      ws_rank[(size_t)t * NTOPK + found];
            if (pos < CAPACITY) {
                cw[j] = ws_prob[(size_t)t * NTOPK + found];
                pr[j] = (float)pos;
                vm[j] = 1.f;
            }
        }
    }
    ((float4*)(out + 2))[gid]          = make_float4(cw[0], cw[1], cw[2], cw[3]);
    ((float4*)(out + 2 + TE))[gid]     = make_float4(pr[0], pr[1], pr[2], pr[3]);
    ((float4*)(out + 2 + 2 * TE))[gid] = make_float4(vm[0], vm[1], vm[2], vm[3]);
}

// ---------------- launch ------------------------------------------------------
extern "C" void kernel_launch(void* const* d_in, const int* in_sizes, int n_in,
                              void* d_out, int out_size, void* d_ws, size_t ws_size,
                              hipStream_t stream) {
    const float* x  = (const float*)d_in[0];   // [16384, 4096] fp32
    const float* wg = (const float*)d_in[1];   // [64, 4096] fp32
    float* out = (float*)d_out;
    char* ws = (char*)d_ws;

    // K-split 8 (32 MB partials) if ws allows, else 4, else 2.
    const int KS = (ws_size >= 40u * 1024u * 1024u) ? 8
                 : (ws_size >= 20u * 1024u * 1024u) ? 4 : 2;
    const size_t lp_bytes = (size_t)KS * TE * 4;

    float* lp   = (float*)(ws);
    char*  rest = ws + lp_bytes;
    int*   idxw = (int*)  (rest);               // 512 KB
    float* prob = (float*)(rest + 524288);      // 512 KB
    int*   rank = (int*)  (rest + 1048576);     // 512 KB
    int*   hist = (int*)  (rest + 1572864);     // 512 KB  [bin][block]
    int*   offs = (int*)  (rest + 2097152);     // 512 KB  [bin][block]
    float* gsum = (float*)(rest + 2621440);     // 64 KB
    int*   tot  = (int*)  (rest + 2686976);     // 2 KB
    int*   base = (int*)  (rest + 2691072);     // 2 KB

    dim3 g1(T_TOK / BT, KS);
    gemm_k<<<g1, 256, 0, stream>>>(x, wg, lp, HID / KS);
    route_k<<<NBLK2, 1024, 0, stream>>>(lp, KS, idxw, prob, rank, hist, gsum);
    scan_k<<<64, 512, 0, stream>>>(hist, offs, tot);
    finalize_k<<<1, 256, 0, stream>>>(tot, gsum, base, out);
    output_k<<<TE / 4 / 256, 256, 0, stream>>>(idxw, prob, rank, offs, base, out);
}

// Round 4
// 444.843 us; speedup vs baseline: 1.3259x; 1.0101x over previous
//
#include <hip/hip_runtime.h>
#include <hip/hip_bf16.h>

#define T_TOK   16384
#define HID     4096
#define NEXP    64
#define NTOPK   8
#define CAPACITY 2048
#define TE      (T_TOK * NEXP)      // 1048576
#define NBLK2   (T_TOK / 64)        // 256 routing blocks
#define BT      128                 // tokens per gemm block-tile
#define BK      32                  // K-tile
#define KS      8                   // K-splits
#define XP      (BT + 4)            // 132: pad -> stride%32==4, 16B-aligned rows
#define WP      (NEXP + 4)          // 68

// ---------------- K1: gate GEMM  lp[split][t][e] ------------------------------
// grid (T/128, 8), block 128 (2 waves). Thread: 8 tokens x 8 experts.
__global__ __launch_bounds__(128, 2) void gemm_k(const float* __restrict__ x,
                                                 const float* __restrict__ wg,
                                                 float* __restrict__ lp) {
    __shared__ float xs[BK][XP];    // [k][t]  16.5 KB
    __shared__ float wsh[BK][WP];   // [k][e]   8.5 KB
    const int tid = threadIdx.x;
    const int tx = tid & 7, ty = tid >> 3;      // expert oct / token oct
    const int t0 = blockIdx.x * BT;
    const int kbase = blockIdx.y * (HID / KS);  // klen = 512
    const int scol = tid & 7;                   // float4 column (k/4)
    const int srow = tid >> 3;                  // base staging row

    float acc[8][8];
#pragma unroll
    for (int i = 0; i < 8; ++i)
#pragma unroll
        for (int j = 0; j < 8; ++j) acc[i][j] = 0.f;

    for (int tile = 0; tile < (HID / KS) / BK; ++tile) {
        const int k0 = kbase + tile * BK;
        float4 xv[8], wv[4];
#pragma unroll
        for (int j = 0; j < 8; ++j)
            xv[j] = *(const float4*)(x + (size_t)(t0 + srow + 16 * j) * HID + k0 + scol * 4);
#pragma unroll
        for (int j = 0; j < 4; ++j)
            wv[j] = *(const float4*)(wg + (size_t)(srow + 16 * j) * HID + k0 + scol * 4);
        __syncthreads();
#pragma unroll
        for (int j = 0; j < 8; ++j) {
            xs[scol * 4 + 0][srow + 16 * j] = xv[j].x;
            xs[scol * 4 + 1][srow + 16 * j] = xv[j].y;
            xs[scol * 4 + 2][srow + 16 * j] = xv[j].z;
            xs[scol * 4 + 3][srow + 16 * j] = xv[j].w;
        }
#pragma unroll
        for (int j = 0; j < 4; ++j) {
            wsh[scol * 4 + 0][srow + 16 * j] = wv[j].x;
            wsh[scol * 4 + 1][srow + 16 * j] = wv[j].y;
            wsh[scol * 4 + 2][srow + 16 * j] = wv[j].z;
            wsh[scol * 4 + 3][srow + 16 * j] = wv[j].w;
        }
        __syncthreads();
#pragma unroll 8
        for (int k = 0; k < BK; ++k) {
            float4 a0 = *(const float4*)(&xs[k][ty * 8]);
            float4 a1 = *(const float4*)(&xs[k][ty * 8 + 4]);
            float4 b0 = *(const float4*)(&wsh[k][tx * 8]);
            float4 b1 = *(const float4*)(&wsh[k][tx * 8 + 4]);
            float ar[8] = {a0.x, a0.y, a0.z, a0.w, a1.x, a1.y, a1.z, a1.w};
            float br[8] = {b0.x, b0.y, b0.z, b0.w, b1.x, b1.y, b1.z, b1.w};
#pragma unroll
            for (int i = 0; i < 8; ++i)
#pragma unroll
                for (int j = 0; j < 8; ++j)
                    acc[i][j] = fmaf(ar[i], br[j], acc[i][j]);
        }
    }
    float* op = lp + (size_t)blockIdx.y * TE + (size_t)(t0 + ty * 8) * NEXP + tx * 8;
#pragma unroll
    for (int i = 0; i < 8; ++i) {
        *(float4*)(op + (size_t)i * NEXP) =
            make_float4(acc[i][0], acc[i][1], acc[i][2], acc[i][3]);
        *(float4*)(op + (size_t)i * NEXP + 4) =
            make_float4(acc[i][4], acc[i][5], acc[i][6], acc[i][7]);
    }
}

// ---------------- K2: softmax + group-limited top-k routing -------------------
// grid T/64, block 1024 (16 waves x 4 tokens each). lane = expert.
__global__ __launch_bounds__(1024) void route_k(const float* __restrict__ lp,
                                                int* __restrict__ ws_idx,
                                                float* __restrict__ ws_prob,
                                                int* __restrict__ ws_rank,
                                                int* __restrict__ ws_hist,
                                                float* __restrict__ ws_gsum) {
    __shared__ unsigned char idx_lds[64][8];
    __shared__ float gsum_lds[16][64];
    const int tid = threadIdx.x, lane = tid & 63, w = tid >> 6;
    const int blk = blockIdx.x;

    float gacc = 0.f;
    for (int i = 0; i < 4; ++i) {
        const int tloc = w * 4 + i;
        const int t = blk * 64 + tloc;
        float lg = 0.f;
        for (int s = 0; s < KS; ++s)
            lg += lp[(size_t)s * TE + (size_t)t * NEXP + lane];
        // softmax over 64 experts
        float m = lg;
#pragma unroll
        for (int off = 32; off; off >>= 1) m = fmaxf(m, __shfl_xor(m, off));
        float p = expf(lg - m);
        float s = p;
#pragma unroll
        for (int off = 32; off; off >>= 1) s += __shfl_xor(s, off);
        float gate = p / s;
        // group scores (max over 8 lanes within group), then top-4 groups
        float gsc = gate;
#pragma unroll
        for (int off = 1; off < 8; off <<= 1) gsc = fmaxf(gsc, __shfl_xor(gsc, off));
        const int g = lane >> 3;
        int grank = 0;
#pragma unroll
        for (int gg = 0; gg < 8; ++gg) {
            float o = __shfl(gsc, gg * 8);
            grank += (o > gsc || (o == gsc && gg < g)) ? 1 : 0;
        }
        float gm = (grank < 4) ? gate : 0.f;
        gacc += gm;
        // top-8 over 64 lanes; ties toward lower lane (lax.top_k)
        unsigned long long key =
            ((unsigned long long)__float_as_uint(gm) << 32) | (unsigned long long)(63 - lane);
        float dsum = 0.f;
        int my_e = 0; float my_v = 0.f;
#pragma unroll
        for (int r = 0; r < NTOPK; ++r) {
            unsigned long long b = key;
#pragma unroll
            for (int off = 32; off; off >>= 1) {
                unsigned long long o = __shfl_xor(b, off);
                b = (o > b) ? o : b;
            }
            int be = 63 - (int)(b & 63ull);
            float bv = __uint_as_float((unsigned)(b >> 32));
            dsum += bv;
            if (lane == r) { my_e = be; my_v = bv; }
            if (lane == be) key = 0ull;
        }
        float denom = fmaxf(dsum, 1.1920929e-7f);
        if (lane < NTOPK) {
            ws_idx[(size_t)t * NTOPK + lane]  = my_e;
            ws_prob[(size_t)t * NTOPK + lane] = my_v / denom;
            idx_lds[tloc][lane] = (unsigned char)my_e;
        }
    }
    gsum_lds[w][lane] = gacc;
    __syncthreads();
    // rank + hist via ballot: wave w<8 handles slot w; lane = token
    if (w < NTOPK) {
        const unsigned long long ltmask = (1ull << lane) - 1ull;
        const int ev = idx_lds[lane][w];
        int rank = 0, hc = 0;
        for (int e0 = 0; e0 < NEXP; ++e0) {
            unsigned long long msk = __ballot(ev == e0);
            if (ev == e0) rank = __popcll(msk & ltmask);
            if (lane == e0) hc = __popcll(msk);
        }
        ws_rank[(size_t)(blk * 64 + lane) * NTOPK + w] = rank;
        ws_hist[(size_t)(w * NEXP + lane) * NBLK2 + blk] = hc;  // [bin][block]
    }
    if (tid < 64) {
        float sg = 0.f;
#pragma unroll
        for (int ww = 0; ww < 16; ++ww) sg += gsum_lds[ww][tid];
        ws_gsum[(size_t)blk * NEXP + tid] = sg;
    }
}

// ---------------- K3a: per-bin exclusive scan, 1 wave per bin -----------------
__global__ __launch_bounds__(512) void scan_k(const int* __restrict__ hist,
                                              int* __restrict__ offs,
                                              int* __restrict__ tot) {
    const int bin = blockIdx.x * 8 + (threadIdx.x >> 6);
    const int lane = threadIdx.x & 63;
    int4 v = ((const int4*)(hist + (size_t)bin * NBLK2))[lane];
    int s = v.x + v.y + v.z + v.w;
    int incl = s;
#pragma unroll
    for (int off = 1; off < 64; off <<= 1) {
        int n = __shfl_up(incl, off);
        if (lane >= off) incl += n;
    }
    int excl = incl - s;
    int4 o;
    o.x = excl; o.y = excl + v.x; o.z = o.y + v.y; o.w = o.z + v.z;
    ((int4*)(offs + (size_t)bin * NBLK2))[lane] = o;
    if (lane == 63) tot[bin] = incl;
}

// ---------------- K3b: slot bases + scalar outputs ----------------------------
__global__ __launch_bounds__(256) void finalize_k(const int* __restrict__ tot,
                                                  const float* __restrict__ gsum,
                                                  int* __restrict__ base,
                                                  float* __restrict__ out) {
    __shared__ int tl[512];
    __shared__ float gl[256];
    const int tid = threadIdx.x;
    for (int i = tid; i < 512; i += 256) tl[i] = tot[i];
    {
        const int e = tid & 63, q = tid >> 6;
        float p = 0.f;
        for (int b = q * 64; b < q * 64 + 64; ++b) p += gsum[(size_t)b * NEXP + e];
        gl[tid] = p;
    }
    __syncthreads();
    for (int i = tid; i < 512; i += 256) {
        const int k = i >> 6, e = i & 63;
        int b = 0;
        for (int kk = 0; kk < k; ++kk) b += tl[kk * NEXP + e];
        base[i] = b;
    }
    if (tid < 64) {
        int cnt = 0;
#pragma unroll
        for (int k = 0; k < NTOPK; ++k) cnt += tl[k * NEXP + tid];
        out[2 + 3 * TE + tid] = (float)cnt;          // exp_counts
        float sg = gl[tid] + gl[64 + tid] + gl[128 + tid] + gl[192 + tid];
        float lx = (float)cnt * sg;
        int vs = cnt < CAPACITY ? cnt : CAPACITY;
#pragma unroll
        for (int off = 32; off; off >>= 1) {
            lx += __shfl_xor(lx, off);
            vs += __shfl_xor(vs, off);
        }
        if (tid == 0) {
            out[0] = 64.0f * lx / 268435456.0f;      // E^2 * sum / T^2
            out[1] = (float)vs / 131072.0f;          // / (T*TOPK)
        }
    }
}

// ---------------- K4: dense [T,64] combine / priority / valid -----------------
__global__ __launch_bounds__(256) void output_k(const int* __restrict__ ws_idx,
                                                const float* __restrict__ ws_prob,
                                                const int* __restrict__ ws_rank,
                                                const int* __restrict__ offs,
                                                const int* __restrict__ base,
                                                float* __restrict__ out) {
    const int gid = blockIdx.x * 256 + threadIdx.x;   // 0..TE/4-1
    const int t = gid >> 4, e0 = (gid & 15) << 2;
    const int4* ip = (const int4*)(ws_idx + (size_t)t * NTOPK);
    int4 ia = ip[0], ib = ip[1];
    int i8[NTOPK] = {ia.x, ia.y, ia.z, ia.w, ib.x, ib.y, ib.z, ib.w};
    float cw[4] = {0.f, 0.f, 0.f, 0.f}, pr[4] = {0.f, 0.f, 0.f, 0.f},
          vm[4] = {0.f, 0.f, 0.f, 0.f};
#pragma unroll
    for (int j = 0; j < 4; ++j) {
        const int e = e0 + j;
        int found = -1;
#pragma unroll
        for (int k = 0; k < NTOPK; ++k) if (i8[k] == e) found = k;
        if (found >= 0) {
            const int bin = found * NEXP + e;
            int pos = base[bin] + offs[(size_t)bin * NBLK2 + (t >> 6)] +
                      ws_rank[(size_t)t * NTOPK + found];
            if (pos < CAPACITY) {
                cw[j] = ws_prob[(size_t)t * NTOPK + found];
                pr[j] = (float)pos;
                vm[j] = 1.f;
            }
        }
    }
    ((float4*)(out + 2))[gid]          = make_float4(cw[0], cw[1], cw[2], cw[3]);
    ((float4*)(out + 2 + TE))[gid]     = make_float4(pr[0], pr[1], pr[2], pr[3]);
    ((float4*)(out + 2 + 2 * TE))[gid] = make_float4(vm[0], vm[1], vm[2], vm[3]);
}

// ---------------- launch ------------------------------------------------------
extern "C" void kernel_launch(void* const* d_in, const int* in_sizes, int n_in,
                              void* d_out, int out_size, void* d_ws, size_t ws_size,
                              hipStream_t stream) {
    const float* x  = (const float*)d_in[0];   // [16384, 4096] fp32
    const float* wg = (const float*)d_in[1];   // [64, 4096] fp32
    float* out = (float*)d_out;
    char* ws = (char*)d_ws;

    const size_t lp_bytes = (size_t)KS * TE * 4;   // 32 MB

    float* lp   = (float*)(ws);
    char*  rest = ws + lp_bytes;
    int*   idxw = (int*)  (rest);               // 512 KB
    float* prob = (float*)(rest + 524288);      // 512 KB
    int*   rank = (int*)  (rest + 1048576);     // 512 KB
    int*   hist = (int*)  (rest + 1572864);     // 512 KB  [bin][block]
    int*   offs = (int*)  (rest + 2097152);     // 512 KB  [bin][block]
    float* gsum = (float*)(rest + 2621440);     // 64 KB
    int*   tot  = (int*)  (rest + 2686976);     // 2 KB
    int*   base = (int*)  (rest + 2691072);     // 2 KB

    dim3 g1(T_TOK / BT, KS);
    gemm_k<<<g1, 128, 0, stream>>>(x, wg, lp);
    route_k<<<NBLK2, 1024, 0, stream>>>(lp, idxw, prob, rank, hist, gsum);
    scan_k<<<64, 512, 0, stream>>>(hist, offs, tot);
    finalize_k<<<1, 256, 0, stream>>>(tot, gsum, base, out);
    output_k<<<TE / 4 / 256, 256, 0, stream>>>(idxw, prob, rank, offs, base, out);
}